// Round 1
// baseline (182.105 us; speedup 1.0000x reference)
//
#include <hip/hip_runtime.h>
#include <cmath>

// Problem constants (fixed by reference): x,y are (16,3,512,512) f32.
constexpr int IMG_H = 512;
constexpr int IMG_W = 512;
constexpr int PLANES = 16 * 3;            // N*C depthwise planes
constexpr int TILE = 32;                  // output tile (square)
constexpr int HALO = 5;                   // WINDOW//2
constexpr int ITILE = TILE + 2 * HALO;    // 42 input tile
constexpr int ISTR = ITILE + 2;           // 44, padded LDS stride for input tiles
constexpr int TILES_PER_SIDE = IMG_W / TILE;  // 16
constexpr long long TOTAL_PIX = (long long)PLANES * IMG_H * IMG_W;  // 12582912

struct GWin { float g[11]; };

__global__ __launch_bounds__(256)
void ssim_fused_kernel(const float* __restrict__ x,
                       const float* __restrict__ y,
                       double* __restrict__ accum,
                       GWin win)
{
    __shared__ float sx[ITILE][ISTR];
    __shared__ float sy[ITILE][ISTR];
    __shared__ float hf[5][ITILE][TILE];   // hx, hy, hxx, hyy, hxy (stride 32: 2-way alias only)

    const int tid = threadIdx.x;
    const int b = blockIdx.x;
    const int tile_c = b & (TILES_PER_SIDE - 1);
    const int tile_r = (b >> 4) & (TILES_PER_SIDE - 1);
    const int plane  = b >> 8;

    const float* __restrict__ xp = x + (size_t)plane * (IMG_H * IMG_W);
    const float* __restrict__ yp = y + (size_t)plane * (IMG_H * IMG_W);

    const int r0 = tile_r * TILE - HALO;
    const int c0 = tile_c * TILE - HALO;

    // ---- stage input tile (zero-padded borders) ----
    for (int i = tid; i < ITILE * ITILE; i += 256) {
        int r = i / ITILE;
        int c = i - r * ITILE;
        int gr = r0 + r, gc = c0 + c;
        float xv = 0.f, yv = 0.f;
        if ((unsigned)gr < (unsigned)IMG_H && (unsigned)gc < (unsigned)IMG_W) {
            size_t off = (size_t)gr * IMG_W + gc;
            xv = xp[off];
            yv = yp[off];
        }
        sx[r][c] = xv;
        sy[r][c] = yv;
    }
    __syncthreads();

    // ---- horizontal 11-tap conv of {x, y, x^2, y^2, xy} ----
    for (int i = tid; i < ITILE * TILE; i += 256) {
        int r = i >> 5;
        int c = i & 31;
        float ax = 0.f, ay = 0.f, axx = 0.f, ayy = 0.f, axy = 0.f;
#pragma unroll
        for (int k = 0; k < 11; ++k) {
            float g = win.g[k];
            float xv = sx[r][c + k];
            float yv = sy[r][c + k];
            ax  += g * xv;
            ay  += g * yv;
            axx += g * xv * xv;
            ayy += g * yv * yv;
            axy += g * xv * yv;
        }
        hf[0][r][c] = ax;
        hf[1][r][c] = ay;
        hf[2][r][c] = axx;
        hf[3][r][c] = ayy;
        hf[4][r][c] = axy;
    }
    __syncthreads();

    // ---- vertical 11-tap conv + SSIM map; each thread: 4 rows of one column ----
    const int c  = tid & 31;
    const int rb = (tid >> 5) * 4;

    float vx[14], vy[14], vxx[14], vyy[14], vxy[14];
#pragma unroll
    for (int k = 0; k < 14; ++k) {
        vx[k]  = hf[0][rb + k][c];
        vy[k]  = hf[1][rb + k][c];
        vxx[k] = hf[2][rb + k][c];
        vyy[k] = hf[3][rb + k][c];
        vxy[k] = hf[4][rb + k][c];
    }

    float lsum = 0.f;
#pragma unroll
    for (int rr = 0; rr < 4; ++rr) {
        float mx = 0.f, my = 0.f, mxx = 0.f, myy = 0.f, mxy = 0.f;
#pragma unroll
        for (int k = 0; k < 11; ++k) {
            float g = win.g[k];
            mx  += g * vx[rr + k];
            my  += g * vy[rr + k];
            mxx += g * vxx[rr + k];
            myy += g * vyy[rr + k];
            mxy += g * vxy[rr + k];
        }
        float mu_x_sq = mx * mx;
        float mu_y_sq = my * my;
        float mu_xy   = mx * my;
        float sig_x  = mxx - mu_x_sq;
        float sig_y  = myy - mu_y_sq;
        float sig_xy = mxy - mu_xy;
        const float C1 = 0.01f * 0.01f;
        const float C2 = 0.03f * 0.03f;
        float n = (2.f * mu_xy + C1) * (2.f * sig_xy + C2);
        float d = (mu_x_sq + mu_y_sq + C1) * (sig_x + sig_y + C2);
        lsum += n / (d + 1e-8f);
    }

    // ---- block reduction: 64-lane shuffle tree, then cross-wave via LDS ----
#pragma unroll
    for (int off = 32; off; off >>= 1) lsum += __shfl_down(lsum, off);

    __shared__ float wsum[4];
    const int lane = tid & 63, wid = tid >> 6;
    if (lane == 0) wsum[wid] = lsum;
    __syncthreads();
    if (tid == 0) {
        float s = wsum[0] + wsum[1] + wsum[2] + wsum[3];
        atomicAdd(accum, (double)s);
    }
}

__global__ void ssim_finalize_kernel(const double* __restrict__ accum,
                                     float* __restrict__ out)
{
    out[0] = (float)(accum[0] / (double)TOTAL_PIX);
}

extern "C" void kernel_launch(void* const* d_in, const int* in_sizes, int n_in,
                              void* d_out, int out_size, void* d_ws, size_t ws_size,
                              hipStream_t stream) {
    const float* x = (const float*)d_in[0];
    const float* y = (const float*)d_in[1];
    float* out = (float*)d_out;
    double* accum = (double*)d_ws;

    // Gaussian window, computed exactly like the reference (f64 math, cast f32).
    GWin win;
    {
        double g[11], s = 0.0;
        for (int i = 0; i < 11; ++i) {
            double d = (double)i - 5.0;
            g[i] = std::exp(-(d * d) / (2.0 * 1.5 * 1.5));
            s += g[i];
        }
        for (int i = 0; i < 11; ++i) win.g[i] = (float)(g[i] / s);
    }

    // zero the double accumulator each call (deterministic; graph-capturable)
    hipMemsetAsync(d_ws, 0, sizeof(double), stream);

    const int nblocks = PLANES * TILES_PER_SIDE * TILES_PER_SIDE;  // 12288
    ssim_fused_kernel<<<nblocks, 256, 0, stream>>>(x, y, accum, win);
    ssim_finalize_kernel<<<1, 1, 0, stream>>>(accum, out);
}

// Round 2
// 178.013 us; speedup vs baseline: 1.0230x; 1.0230x over previous
//
#include <hip/hip_runtime.h>
#include <cmath>

// x,y: (16,3,512,512) f32. SSIM with separable 11-tap Gaussian, fused, scalar-mean output.
constexpr int IMG_H = 512;
constexpr int IMG_W = 512;
constexpr int PLANES = 16 * 3;
constexpr int TILE = 32;                  // output tile (square)
constexpr int HALO = 5;
constexpr int ITILE = TILE + 2 * HALO;    // 42
constexpr int ISTR = ITILE + 2;           // 44 floats: pad for staging tiles
constexpr int HSTR = 44;                  // hf row stride: 42 used; 176B = 16B-aligned + bank spread
constexpr int TPS = IMG_W / TILE;         // 16
constexpr long long TOTAL_PIX = (long long)PLANES * IMG_H * IMG_W;

struct GWin { float g[11]; };

__global__ __launch_bounds__(256)
void ssim_fused_kernel(const float* __restrict__ x,
                       const float* __restrict__ y,
                       double* __restrict__ accum,
                       GWin win)
{
    __shared__ float sx[ITILE][ISTR];
    __shared__ float sy[ITILE][ISTR];
    __shared__ __align__(16) float hf[5][TILE][HSTR];  // v-conv of {x,y,xx,yy,xy}: 32 rows x 42 cols

    const int tid = threadIdx.x;
    const int b = blockIdx.x;
    const int tile_c = b & (TPS - 1);
    const int tile_r = (b >> 4) & (TPS - 1);
    const int plane  = b >> 8;

    const float* __restrict__ xp = x + (size_t)plane * (IMG_H * IMG_W);
    const float* __restrict__ yp = y + (size_t)plane * (IMG_H * IMG_W);

    const int r0 = tile_r * TILE - HALO;
    const int c0 = tile_c * TILE - HALO;

    // ---- stage 42x42 input tile (zero-padded at image borders) ----
    for (int i = tid; i < ITILE * ITILE; i += 256) {
        int r = i / ITILE;
        int c = i - r * ITILE;
        int gr = r0 + r, gc = c0 + c;
        float xv = 0.f, yv = 0.f;
        if ((unsigned)gr < (unsigned)IMG_H && (unsigned)gc < (unsigned)IMG_W) {
            size_t off = (size_t)gr * IMG_W + gc;
            xv = xp[off];
            yv = yp[off];
        }
        sx[r][c] = xv;
        sy[r][c] = yv;
    }
    __syncthreads();

    // ---- pass V: vertical 11-tap conv of {x,y,xx,yy,xy}; reads only x,y ----
    // 168 threads: col c in [0,42), row-group rg in [0,4) -> 8 output rows each.
    if (tid < 4 * ITILE) {
        const int rg = tid / ITILE;
        const int c  = tid - rg * ITILE;
        const int rbase = rg * 8;

        float xw[18], yw[18];
#pragma unroll
        for (int k = 0; k < 18; ++k) {
            xw[k] = sx[rbase + k][c];
            yw[k] = sy[rbase + k][c];
        }
#pragma unroll
        for (int rr = 0; rr < 8; ++rr) {
            float ax = 0.f, ay = 0.f, axx = 0.f, ayy = 0.f, axy = 0.f;
#pragma unroll
            for (int k = 0; k < 11; ++k) {
                float g = win.g[k];
                float xv = xw[rr + k];
                float yv = yw[rr + k];
                ax  += g * xv;
                ay  += g * yv;
                axx += g * (xv * xv);
                ayy += g * (yv * yv);
                axy += g * (xv * yv);
            }
            hf[0][rbase + rr][c] = ax;
            hf[1][rbase + rr][c] = ay;
            hf[2][rbase + rr][c] = axx;
            hf[3][rbase + rr][c] = ayy;
            hf[4][rbase + rr][c] = axy;
        }
    }
    __syncthreads();

    // ---- pass H: horizontal 11-tap conv via b128 sliding windows + SSIM ----
    // thread -> row hr (0..31), quad q (0..7): output cols 4q..4q+3.
    const int hr = tid >> 3;
    const int q  = tid & 7;

    float acc[5][4];
#pragma unroll
    for (int f = 0; f < 5; ++f) {
        const float4* rowv = (const float4*)&hf[f][hr][0];
        float4 v0 = rowv[q];
        float4 v1 = rowv[q + 1];
        float4 v2 = rowv[q + 2];
        float4 v3 = rowv[q + 3];
        float w[16] = { v0.x, v0.y, v0.z, v0.w,
                        v1.x, v1.y, v1.z, v1.w,
                        v2.x, v2.y, v2.z, v2.w,
                        v3.x, v3.y, v3.z, v3.w };
#pragma unroll
        for (int j = 0; j < 4; ++j) {
            float a = 0.f;
#pragma unroll
            for (int k = 0; k < 11; ++k) a += win.g[k] * w[j + k];
            acc[f][j] = a;
        }
    }

    float lsum = 0.f;
#pragma unroll
    for (int j = 0; j < 4; ++j) {
        float mx  = acc[0][j];
        float my  = acc[1][j];
        float mxx = acc[2][j];
        float myy = acc[3][j];
        float mxy = acc[4][j];
        float mu_x_sq = mx * mx;
        float mu_y_sq = my * my;
        float mu_xy   = mx * my;
        float sig_x  = mxx - mu_x_sq;
        float sig_y  = myy - mu_y_sq;
        float sig_xy = mxy - mu_xy;
        const float C1 = 0.01f * 0.01f;
        const float C2 = 0.03f * 0.03f;
        float n = (2.f * mu_xy + C1) * (2.f * sig_xy + C2);
        float d = (mu_x_sq + mu_y_sq + C1) * (sig_x + sig_y + C2);
        lsum += n / (d + 1e-8f);
    }

    // ---- block reduction ----
#pragma unroll
    for (int off = 32; off; off >>= 1) lsum += __shfl_down(lsum, off);

    __shared__ float wsum[4];
    const int lane = tid & 63, wid = tid >> 6;
    if (lane == 0) wsum[wid] = lsum;
    __syncthreads();
    if (tid == 0) {
        float s = wsum[0] + wsum[1] + wsum[2] + wsum[3];
        atomicAdd(accum, (double)s);
    }
}

__global__ void ssim_finalize_kernel(const double* __restrict__ accum,
                                     float* __restrict__ out)
{
    out[0] = (float)(accum[0] / (double)TOTAL_PIX);
}

extern "C" void kernel_launch(void* const* d_in, const int* in_sizes, int n_in,
                              void* d_out, int out_size, void* d_ws, size_t ws_size,
                              hipStream_t stream) {
    const float* x = (const float*)d_in[0];
    const float* y = (const float*)d_in[1];
    float* out = (float*)d_out;
    double* accum = (double*)d_ws;

    GWin win;
    {
        double g[11], s = 0.0;
        for (int i = 0; i < 11; ++i) {
            double d = (double)i - 5.0;
            g[i] = std::exp(-(d * d) / (2.0 * 1.5 * 1.5));
            s += g[i];
        }
        for (int i = 0; i < 11; ++i) win.g[i] = (float)(g[i] / s);
    }

    hipMemsetAsync(d_ws, 0, sizeof(double), stream);

    const int nblocks = PLANES * TPS * TPS;  // 12288
    ssim_fused_kernel<<<nblocks, 256, 0, stream>>>(x, y, accum, win);
    ssim_finalize_kernel<<<1, 1, 0, stream>>>(accum, out);
}